// Round 1
// baseline (430.106 us; speedup 1.0000x reference)
//
#include <hip/hip_runtime.h>
#include <hip/hip_bf16.h>
#include <stdint.h>

#define DIMN 1024
#define HEADS 16
#define HD 64
#define BATCH 4
#define SEQ 4096
#define M_TOT (BATCH*SEQ)   // 16384

typedef __attribute__((ext_vector_type(8))) __bf16 bf16x8;
typedef __attribute__((ext_vector_type(4))) __bf16 bf16x4;
typedef __attribute__((ext_vector_type(4))) float f32x4;

__device__ __forceinline__ void gload_lds16(const void* g, void* l) {
  __builtin_amdgcn_global_load_lds(
      (const __attribute__((address_space(1))) void*)(uintptr_t)g,
      (__attribute__((address_space(3))) void*)(uint32_t)(uintptr_t)l,
      16, 0, 0);
}

// ---------------- cast kernels ----------------
__global__ __launch_bounds__(256) void cast_x_kernel(const float* __restrict__ in,
                                                     __bf16* __restrict__ out, int n4) {
  int i = blockIdx.x * 256 + threadIdx.x;
  if (i < n4) {
    f32x4 v = ((const f32x4*)in)[i];
    bf16x4 o;
    o[0] = (__bf16)v[0]; o[1] = (__bf16)v[1]; o[2] = (__bf16)v[2]; o[3] = (__bf16)v[3];
    ((bf16x4*)out)[i] = o;
  }
}

__global__ __launch_bounds__(256) void cast_w4_kernel(const float* __restrict__ a,
                                                      const float* __restrict__ b,
                                                      const float* __restrict__ c,
                                                      const float* __restrict__ d,
                                                      __bf16* __restrict__ oa,
                                                      __bf16* __restrict__ ob,
                                                      __bf16* __restrict__ oc,
                                                      __bf16* __restrict__ od) {
  const float* srcs[4] = {a, b, c, d};
  __bf16* dsts[4] = {oa, ob, oc, od};
  const float* src = srcs[blockIdx.y];
  __bf16* dst = dsts[blockIdx.y];
  int i = blockIdx.x * 256 + threadIdx.x;   // n4 = 1024*1024/4 = 262144, grid.x = 1024
  f32x4 v = ((const f32x4*)src)[i];
  bf16x4 o;
  o[0] = (__bf16)v[0]; o[1] = (__bf16)v[1]; o[2] = (__bf16)v[2]; o[3] = (__bf16)v[3];
  ((bf16x4*)dst)[i] = o;
}

// ---------------- GEMM: C = A[M,K] @ W[N,K]^T ----------------
// MODE 0: elu(v)+1 -> bf16, head layout [b,h,s,64]
// MODE 1: v        -> bf16, head layout [b,h,s,64]
// MODE 2: v + bias -> f32, row-major [M, N]
#define BM 128
#define BN 128
#define BK 32

template <int MODE>
__global__ __launch_bounds__(256) void gemm_bt(const __bf16* __restrict__ A,
                                               const __bf16* __restrict__ Bw,
                                               void* __restrict__ Cout,
                                               const float* __restrict__ bias) {
  __shared__ __bf16 As[BM][BK];   // 8 KB
  __shared__ __bf16 Bs[BN][BK];   // 8 KB
  const int K = DIMN;
  const int bid = blockIdx.x;          // 128*8 tiles
  const int m0 = (bid >> 3) * BM;
  const int n0 = (bid & 7) * BN;
  const int tid = threadIdx.x;
  const int lane = tid & 63;
  const int wave = tid >> 6;
  const int wr = wave >> 1, wc = wave & 1;

  f32x4 acc[4][4] = {};

  for (int k0 = 0; k0 < K; k0 += BK) {
#pragma unroll
    for (int t = 0; t < 2; ++t) {
      int chunk = t * 4 + wave;                  // 0..7, wave-uniform
      int e = (chunk * 1024 + lane * 16) >> 1;   // element offset in tile
      int row = e >> 5, col = e & 31;            // 32 elems per row
      gload_lds16(A  + (size_t)(m0 + row) * K + k0 + col, ((char*)&As[0][0]) + chunk * 1024);
      gload_lds16(Bw + (size_t)(n0 + row) * K + k0 + col, ((char*)&Bs[0][0]) + chunk * 1024);
    }
    __syncthreads();

    bf16x8 af[4], bf[4];
#pragma unroll
    for (int i = 0; i < 4; ++i) {
      af[i] = *(const bf16x8*)&As[wr * 64 + i * 16 + (lane & 15)][(lane >> 4) * 8];
      bf[i] = *(const bf16x8*)&Bs[wc * 64 + i * 16 + (lane & 15)][(lane >> 4) * 8];
    }
#pragma unroll
    for (int i = 0; i < 4; ++i)
#pragma unroll
      for (int j = 0; j < 4; ++j)
        acc[i][j] = __builtin_amdgcn_mfma_f32_16x16x32_bf16(af[i], bf[j], acc[i][j], 0, 0, 0);
    __syncthreads();
  }

  // epilogue: D[i][j] -> col = lane&15, row = (lane>>4)*4 + reg   [measured m89]
#pragma unroll
  for (int i = 0; i < 4; ++i) {
#pragma unroll
    for (int j = 0; j < 4; ++j) {
#pragma unroll
      for (int r = 0; r < 4; ++r) {
        int row = m0 + wr * 64 + i * 16 + (lane >> 4) * 4 + r;
        int col = n0 + wc * 64 + j * 16 + (lane & 15);
        float v = acc[i][j][r];
        if (MODE == 2) {
          ((float*)Cout)[(size_t)row * DIMN + col] = v + bias[col];
        } else {
          if (MODE == 0) v = (v > 0.f) ? (v + 1.f) : __expf(v);
          int b = row >> 12, s = row & 4095;
          int h = col >> 6, e2 = col & 63;
          ((__bf16*)Cout)[((size_t)((b * HEADS + h) * SEQ + s)) * HD + e2] = (__bf16)v;
        }
      }
    }
  }
}

// ---------------- kv_state / k_state ----------------
// kv[bh][d][e] = sum_n kp[bh,n,d] * vb[bh,n,e];  ks[bh][d] = sum_n kp[bh,n,d]
__global__ __launch_bounds__(256) void kv_state_kernel(const __bf16* __restrict__ kp,
                                                       const __bf16* __restrict__ vb,
                                                       float* __restrict__ kv,
                                                       float* __restrict__ ks) {
  __shared__ float kt[64][64];   // 16 KB
  __shared__ float vt[64][64];   // 16 KB
  const int bid = blockIdx.x;    // 64 bh * 4 chunks
  const int bh = bid >> 2, nc = bid & 3;
  const int tid = threadIdx.x;
  const int td = tid >> 4, te = tid & 15;

  float acc[4][4] = {};
  float kacc[4] = {};

  for (int nt = 0; nt < 16; ++nt) {
    int n0 = nc * 1024 + nt * 64;
#pragma unroll
    for (int t = 0; t < 2; ++t) {
      int idx = (t * 256 + tid) * 8;     // element in 64x64 tile
      int rr = idx >> 6, cc = idx & 63;
      size_t gb = ((size_t)bh * SEQ + n0 + rr) * HD + cc;
      bf16x8 kk = *(const bf16x8*)(kp + gb);
      bf16x8 vv = *(const bf16x8*)(vb + gb);
#pragma unroll
      for (int j = 0; j < 8; ++j) {
        kt[rr][cc + j] = (float)kk[j];
        vt[rr][cc + j] = (float)vv[j];
      }
    }
    __syncthreads();

    for (int n = 0; n < 64; ++n) {
      float kd[4], ve[4];
#pragma unroll
      for (int i = 0; i < 4; ++i) { kd[i] = kt[n][td * 4 + i]; ve[i] = vt[n][te * 4 + i]; }
#pragma unroll
      for (int i = 0; i < 4; ++i)
#pragma unroll
        for (int j = 0; j < 4; ++j) acc[i][j] += kd[i] * ve[j];
      if (te == 0) {
#pragma unroll
        for (int i = 0; i < 4; ++i) kacc[i] += kd[i];
      }
    }
    __syncthreads();
  }

#pragma unroll
  for (int i = 0; i < 4; ++i)
#pragma unroll
    for (int j = 0; j < 4; ++j)
      atomicAdd(&kv[(size_t)bh * 4096 + (td * 4 + i) * 64 + te * 4 + j], acc[i][j]);
  if (te == 0) {
#pragma unroll
    for (int i = 0; i < 4; ++i) atomicAdd(&ks[bh * 64 + td * 4 + i], kacc[i]);
  }
}

// ---------------- attn_out + depthwise conv -> y (bf16) ----------------
__global__ __launch_bounds__(256) void attn_local_kernel(const __bf16* __restrict__ qp,
                                                         const float* __restrict__ kv,
                                                         const float* __restrict__ ks,
                                                         const float* __restrict__ x,
                                                         const float* __restrict__ conv_w,
                                                         const float* __restrict__ conv_b,
                                                         __bf16* __restrict__ y) {
  __shared__ float kvs[HD][HD];   // 16 KB
  __shared__ float kss[HD];
  const int bid = blockIdx.x;     // 64 bh * 16 chunks
  const int bh = bid >> 4;
  const int chunk = bid & 15;
  const int tid = threadIdx.x;
  const int lane = tid & 63;
  const int wave = tid >> 6;

  for (int i = tid; i < HD * HD; i += 256) kvs[i >> 6][i & 63] = kv[(size_t)bh * 4096 + i];
  if (tid < HD) kss[tid] = ks[bh * 64 + tid];
  __syncthreads();

  const int b = bh >> 4, h = bh & 15;
  for (int r = 0; r < 64; ++r) {
    int s = chunk * 256 + wave * 64 + r;
    const __bf16* qrow = qp + ((size_t)bh * SEQ + s) * HD;
    float acc = 0.f, den = 0.f;
#pragma unroll
    for (int d0 = 0; d0 < HD; d0 += 8) {
      bf16x8 qv = *(const bf16x8*)(qrow + d0);
#pragma unroll
      for (int j = 0; j < 8; ++j) {
        float qf = (float)qv[j];
        acc += qf * kvs[d0 + j][lane];
        den += qf * kss[d0 + j];
      }
    }
    float val = acc / fmaxf(den, 1e-6f);

    int c = h * HD + lane;
    size_t m = (size_t)b * SEQ + s;
    float xm = x[m * DIMN + c];
    float xl = (s > 0)       ? x[(m - 1) * DIMN + c] : 0.f;
    float xr = (s < SEQ - 1) ? x[(m + 1) * DIMN + c] : 0.f;
    float loc = xl * conv_w[c * 3 + 0] + xm * conv_w[c * 3 + 1] + xr * conv_w[c * 3 + 2] + conv_b[c];
    y[m * DIMN + c] = (__bf16)(val + loc);
  }
}

// ---------------- launch ----------------
extern "C" void kernel_launch(void* const* d_in, const int* in_sizes, int n_in,
                              void* d_out, int out_size, void* d_ws, size_t ws_size,
                              hipStream_t stream) {
  const float* x  = (const float*)d_in[0];
  const float* Wq = (const float*)d_in[1];
  const float* Wk = (const float*)d_in[2];
  const float* Wv = (const float*)d_in[3];
  const float* Wp = (const float*)d_in[4];
  const float* bp = (const float*)d_in[5];
  const float* cw = (const float*)d_in[6];
  const float* cb = (const float*)d_in[7];
  float* out = (float*)d_out;

  char* ws = (char*)d_ws;
  const size_t MB = 1024 * 1024;
  __bf16* xb  = (__bf16*)(ws);             // 32 MB (A for QKV gemms)
  __bf16* y   = xb;                        // alias: y written after xb last use
  __bf16* qp  = (__bf16*)(ws + 32 * MB);   // 32 MB  [b,h,s,64]
  __bf16* kp  = (__bf16*)(ws + 64 * MB);   // 32 MB
  __bf16* vb  = (__bf16*)(ws + 96 * MB);   // 32 MB
  __bf16* wqb = (__bf16*)(ws + 128 * MB);  // 2 MB each
  __bf16* wkb = (__bf16*)(ws + 130 * MB);
  __bf16* wvb = (__bf16*)(ws + 132 * MB);
  __bf16* wpb = (__bf16*)(ws + 134 * MB);
  float*  kv  = (float*)(ws + 136 * MB);   // 1 MB f32 [64][64][64]
  float*  ks  = (float*)(ws + 137 * MB);   // 16 KB f32

  cast_x_kernel<<<M_TOT * DIMN / 4 / 256, 256, 0, stream>>>(x, xb, M_TOT * DIMN / 4);
  cast_w4_kernel<<<dim3(1024, 4), 256, 0, stream>>>(Wq, Wk, Wv, Wp, wqb, wkb, wvb, wpb);

  gemm_bt<0><<<1024, 256, 0, stream>>>(xb, wqb, qp, nullptr);
  gemm_bt<0><<<1024, 256, 0, stream>>>(xb, wkb, kp, nullptr);
  gemm_bt<1><<<1024, 256, 0, stream>>>(xb, wvb, vb, nullptr);

  hipMemsetAsync(kv, 0, 64 * 4096 * 4 + 64 * 64 * 4, stream);
  kv_state_kernel<<<256, 256, 0, stream>>>(kp, vb, kv, ks);

  attn_local_kernel<<<1024, 256, 0, stream>>>(qp, kv, ks, x, cw, cb, y);

  gemm_bt<2><<<1024, 256, 0, stream>>>(y, wpb, out, bp);
}

// Round 2
// 359.974 us; speedup vs baseline: 1.1948x; 1.1948x over previous
//
#include <hip/hip_runtime.h>
#include <hip/hip_bf16.h>
#include <stdint.h>

#define DIMN 1024
#define HEADS 16
#define HD 64
#define BATCH 4
#define SEQ 4096
#define M_TOT (BATCH*SEQ)   // 16384

typedef __attribute__((ext_vector_type(8))) __bf16 bf16x8;
typedef __attribute__((ext_vector_type(4))) __bf16 bf16x4;
typedef __attribute__((ext_vector_type(4))) float f32x4;

__device__ __forceinline__ void gload_lds16(const void* g, void* l) {
  __builtin_amdgcn_global_load_lds(
      (const __attribute__((address_space(1))) void*)(uintptr_t)g,
      (__attribute__((address_space(3))) void*)(uint32_t)(uintptr_t)l,
      16, 0, 0);
}

// XOR swizzle for 128B-row tiles (involution on bits 4..6, rows = bit 7+)
__device__ __forceinline__ uint32_t swz128(uint32_t off) {
  return off ^ (((off >> 7) & 7) << 4);
}

// ---------------- cast kernels ----------------
__global__ __launch_bounds__(256) void cast_x_kernel(const float* __restrict__ in,
                                                     __bf16* __restrict__ out, int n4) {
  int i = blockIdx.x * 256 + threadIdx.x;
  if (i < n4) {
    f32x4 v = ((const f32x4*)in)[i];
    bf16x4 o;
    o[0] = (__bf16)v[0]; o[1] = (__bf16)v[1]; o[2] = (__bf16)v[2]; o[3] = (__bf16)v[3];
    ((bf16x4*)out)[i] = o;
  }
}

__global__ __launch_bounds__(256) void cast_w4_kernel(const float* __restrict__ a,
                                                      const float* __restrict__ b,
                                                      const float* __restrict__ c,
                                                      const float* __restrict__ d,
                                                      __bf16* __restrict__ oa,
                                                      __bf16* __restrict__ ob,
                                                      __bf16* __restrict__ oc,
                                                      __bf16* __restrict__ od) {
  const float* srcs[4] = {a, b, c, d};
  __bf16* dsts[4] = {oa, ob, oc, od};
  const float* src = srcs[blockIdx.y];
  __bf16* dst = dsts[blockIdx.y];
  int i = blockIdx.x * 256 + threadIdx.x;
  f32x4 v = ((const f32x4*)src)[i];
  bf16x4 o;
  o[0] = (__bf16)v[0]; o[1] = (__bf16)v[1]; o[2] = (__bf16)v[2]; o[3] = (__bf16)v[3];
  ((bf16x4*)dst)[i] = o;
}

// ---------------- GEMM: C = A[M,K] @ W[N,K]^T ----------------
#define BM 128
#define BN 128
#define BK 32

template <int MODE>  // 0: elu+1 -> bf16 heads; 1: bf16 heads; 2: +bias -> f32
__global__ __launch_bounds__(256) void gemm_bt(const __bf16* __restrict__ A,
                                               const __bf16* __restrict__ Bw,
                                               void* __restrict__ Cout,
                                               const float* __restrict__ bias) {
  __shared__ __bf16 As[BM][BK];
  __shared__ __bf16 Bs[BN][BK];
  const int K = DIMN;
  const int bid = blockIdx.x;
  const int m0 = (bid >> 3) * BM;
  const int n0 = (bid & 7) * BN;
  const int tid = threadIdx.x;
  const int lane = tid & 63;
  const int wave = tid >> 6;
  const int wr = wave >> 1, wc = wave & 1;

  f32x4 acc[4][4] = {};

  for (int k0 = 0; k0 < K; k0 += BK) {
#pragma unroll
    for (int t = 0; t < 2; ++t) {
      int chunk = t * 4 + wave;
      int e = (chunk * 1024 + lane * 16) >> 1;
      int row = e >> 5, col = e & 31;
      gload_lds16(A  + (size_t)(m0 + row) * K + k0 + col, ((char*)&As[0][0]) + chunk * 1024);
      gload_lds16(Bw + (size_t)(n0 + row) * K + k0 + col, ((char*)&Bs[0][0]) + chunk * 1024);
    }
    __syncthreads();

    bf16x8 af[4], bfr[4];
#pragma unroll
    for (int i = 0; i < 4; ++i) {
      af[i]  = *(const bf16x8*)&As[wr * 64 + i * 16 + (lane & 15)][(lane >> 4) * 8];
      bfr[i] = *(const bf16x8*)&Bs[wc * 64 + i * 16 + (lane & 15)][(lane >> 4) * 8];
    }
#pragma unroll
    for (int i = 0; i < 4; ++i)
#pragma unroll
      for (int j = 0; j < 4; ++j)
        acc[i][j] = __builtin_amdgcn_mfma_f32_16x16x32_bf16(af[i], bfr[j], acc[i][j], 0, 0, 0);
    __syncthreads();
  }

#pragma unroll
  for (int i = 0; i < 4; ++i) {
#pragma unroll
    for (int j = 0; j < 4; ++j) {
#pragma unroll
      for (int r = 0; r < 4; ++r) {
        int row = m0 + wr * 64 + i * 16 + (lane >> 4) * 4 + r;
        int col = n0 + wc * 64 + j * 16 + (lane & 15);
        float v = acc[i][j][r];
        if (MODE == 2) {
          ((float*)Cout)[(size_t)row * DIMN + col] = v + bias[col];
        } else {
          if (MODE == 0) v = (v > 0.f) ? (v + 1.f) : __expf(v);
          int b = row >> 12, s = row & 4095;
          int h = col >> 6, e2 = col & 63;
          ((__bf16*)Cout)[((size_t)((b * HEADS + h) * SEQ + s)) * HD + e2] = (__bf16)v;
        }
      }
    }
  }
}

// ---------------- kv_state / k_state ----------------
__global__ __launch_bounds__(256) void kv_state_kernel(const __bf16* __restrict__ kp,
                                                       const __bf16* __restrict__ vb,
                                                       float* __restrict__ kv,
                                                       float* __restrict__ ks) {
  __shared__ float kt[64][64];
  __shared__ float vt[64][64];
  const int bid = blockIdx.x;    // 64 bh * 8 chunks
  const int bh = bid >> 3, nc = bid & 7;
  const int tid = threadIdx.x;
  const int td = tid >> 4, te = tid & 15;

  float acc[4][4] = {};
  float kacc[4] = {};

  for (int nt = 0; nt < 8; ++nt) {
    int n0 = nc * 512 + nt * 64;
#pragma unroll
    for (int t = 0; t < 2; ++t) {
      int idx = (t * 256 + tid) * 8;
      int rr = idx >> 6, cc = idx & 63;
      size_t gb = ((size_t)bh * SEQ + n0 + rr) * HD + cc;
      bf16x8 kk = *(const bf16x8*)(kp + gb);
      bf16x8 vv = *(const bf16x8*)(vb + gb);
      f32x4 a0, a1, b0, b1;
#pragma unroll
      for (int j = 0; j < 4; ++j) {
        a0[j] = (float)kk[j]; a1[j] = (float)kk[j + 4];
        b0[j] = (float)vv[j]; b1[j] = (float)vv[j + 4];
      }
      *(f32x4*)&kt[rr][cc]     = a0; *(f32x4*)&kt[rr][cc + 4] = a1;
      *(f32x4*)&vt[rr][cc]     = b0; *(f32x4*)&vt[rr][cc + 4] = b1;
    }
    __syncthreads();

    for (int n = 0; n < 64; ++n) {
      f32x4 kd = *(const f32x4*)&kt[n][td * 4];
      f32x4 ve = *(const f32x4*)&vt[n][te * 4];
#pragma unroll
      for (int i = 0; i < 4; ++i)
#pragma unroll
        for (int j = 0; j < 4; ++j) acc[i][j] += kd[i] * ve[j];
      if (te == 0) {
#pragma unroll
        for (int i = 0; i < 4; ++i) kacc[i] += kd[i];
      }
    }
    __syncthreads();
  }

#pragma unroll
  for (int i = 0; i < 4; ++i)
#pragma unroll
    for (int j = 0; j < 4; ++j)
      atomicAdd(&kv[(size_t)bh * 4096 + (td * 4 + i) * 64 + te * 4 + j], acc[i][j]);
  if (te == 0) {
#pragma unroll
    for (int i = 0; i < 4; ++i) atomicAdd(&ks[bh * 64 + td * 4 + i], kacc[i]);
  }
}

// ---------------- prep: kvb[bh][80][64] bf16 = {kv^T ; k_state ; 0-pad} ----------------
__global__ __launch_bounds__(256) void prep_kv_kernel(const float* __restrict__ kv,
                                                      const float* __restrict__ ks,
                                                      __bf16* __restrict__ kvb) {
  const int bh = blockIdx.x;
  const int tid = threadIdx.x;
  for (int idx = tid; idx < 80 * 64; idx += 256) {
    int e = idx >> 6, d = idx & 63;
    float v;
    if (e < 64)       v = kv[(size_t)bh * 4096 + d * 64 + e];
    else if (e == 64) v = ks[bh * 64 + d];
    else              v = 0.f;
    kvb[(size_t)bh * 5120 + idx] = (__bf16)v;
  }
}

// ---------------- attn_out (MFMA) + depthwise conv -> y (bf16) ----------------
// per block: one bh, 128 seq rows. B-operand = kvb tile [80][64] (cols 64..79: den+pad)
__global__ __launch_bounds__(256) void attn_local_mfma(const __bf16* __restrict__ qp,
                                                       const __bf16* __restrict__ kvb,
                                                       const float* __restrict__ x,
                                                       const float* __restrict__ conv_w,
                                                       const float* __restrict__ conv_b,
                                                       __bf16* __restrict__ y) {
  __shared__ __bf16 qs[128 * 64];   // 16 KB, swizzled
  __shared__ __bf16 bs[80 * 64];    // 10 KB, swizzled
  const int bid = blockIdx.x;       // 64 bh * 32 chunks
  const int bh = bid >> 5;
  const int chunk = bid & 31;
  const int tid = threadIdx.x;
  const int lane = tid & 63;
  const int wave = tid >> 6;
  const int r16 = lane & 15, r4 = lane >> 4;

  const char* qbase  = (const char*)(qp + ((size_t)bh * SEQ + chunk * 128) * HD);
  const char* kvbase = (const char*)(kvb + (size_t)bh * 5120);
#pragma unroll
  for (int t = 0; t < 4; ++t) {
    int c = t * 4 + wave;
    uint32_t off = c * 1024 + lane * 16;
    gload_lds16(qbase + swz128(off), ((char*)qs) + off);
  }
#pragma unroll
  for (int t = 0; t < 3; ++t) {
    int c = t * 4 + wave;
    if (c < 10) {
      uint32_t off = c * 1024 + lane * 16;
      gload_lds16(kvbase + swz128(off), ((char*)bs) + off);
    }
  }
  __syncthreads();

  f32x4 acc[2][5] = {};
#pragma unroll
  for (int kstep = 0; kstep < 2; ++kstep) {
    bf16x8 af[2], bfr[5];
#pragma unroll
    for (int i = 0; i < 2; ++i) {
      uint32_t off = (wave * 32 + i * 16 + r16) * 128 + kstep * 64 + r4 * 16;
      af[i] = *(const bf16x8*)(((char*)qs) + swz128(off));
    }
#pragma unroll
    for (int j = 0; j < 5; ++j) {
      uint32_t off = (j * 16 + r16) * 128 + kstep * 64 + r4 * 16;
      bfr[j] = *(const bf16x8*)(((char*)bs) + swz128(off));
    }
#pragma unroll
    for (int i = 0; i < 2; ++i)
#pragma unroll
      for (int j = 0; j < 5; ++j)
        acc[i][j] = __builtin_amdgcn_mfma_f32_16x16x32_bf16(af[i], bfr[j], acc[i][j], 0, 0, 0);
  }

  // epilogue: fused 1/den, depthwise conv, y-write
  const int b = bh >> 4, h = bh & 15;
  float w0[4], w1[4], w2[4], bb[4];
#pragma unroll
  for (int j = 0; j < 4; ++j) {
    int c = h * HD + j * 16 + r16;
    w0[j] = conv_w[c * 3 + 0]; w1[j] = conv_w[c * 3 + 1]; w2[j] = conv_w[c * 3 + 2];
    bb[j] = conv_b[c];
  }
#pragma unroll
  for (int i = 0; i < 2; ++i) {
#pragma unroll
    for (int r = 0; r < 4; ++r) {
      int s = chunk * 128 + wave * 32 + i * 16 + r4 * 4 + r;
      size_t m = (size_t)b * SEQ + s;
      float den = fmaxf(__shfl(acc[i][4][r], lane & 48), 1e-6f);
      float inv = 1.0f / den;
#pragma unroll
      for (int j = 0; j < 4; ++j) {
        int c = h * HD + j * 16 + r16;
        float xm = x[m * DIMN + c];
        float xl = (s > 0)       ? x[(m - 1) * DIMN + c] : 0.f;
        float xr = (s < SEQ - 1) ? x[(m + 1) * DIMN + c] : 0.f;
        float val = acc[i][j][r] * inv
                  + xl * w0[j] + xm * w1[j] + xr * w2[j] + bb[j];
        y[m * DIMN + c] = (__bf16)val;
      }
    }
  }
}

// ---------------- launch ----------------
extern "C" void kernel_launch(void* const* d_in, const int* in_sizes, int n_in,
                              void* d_out, int out_size, void* d_ws, size_t ws_size,
                              hipStream_t stream) {
  const float* x  = (const float*)d_in[0];
  const float* Wq = (const float*)d_in[1];
  const float* Wk = (const float*)d_in[2];
  const float* Wv = (const float*)d_in[3];
  const float* Wp = (const float*)d_in[4];
  const float* bp = (const float*)d_in[5];
  const float* cw = (const float*)d_in[6];
  const float* cb = (const float*)d_in[7];
  float* out = (float*)d_out;

  char* ws = (char*)d_ws;
  const size_t MB = 1024 * 1024;
  __bf16* xb  = (__bf16*)(ws);             // 32 MB (A for QKV gemms; later aliased as y)
  __bf16* y   = xb;
  __bf16* qp  = (__bf16*)(ws + 32 * MB);   // [b,h,s,64]
  __bf16* kp  = (__bf16*)(ws + 64 * MB);
  __bf16* vb  = (__bf16*)(ws + 96 * MB);
  __bf16* wqb = (__bf16*)(ws + 128 * MB);
  __bf16* wkb = (__bf16*)(ws + 130 * MB);
  __bf16* wvb = (__bf16*)(ws + 132 * MB);
  __bf16* wpb = (__bf16*)(ws + 134 * MB);
  float*  kv  = (float*)(ws + 136 * MB);   // f32 [64][64][64]
  float*  ks  = (float*)(ws + 137 * MB);   // f32 [64][64]
  __bf16* kvb = wqb;                       // reuse: wqb dead after q-GEMM (655 KB needed)

  cast_x_kernel<<<M_TOT * DIMN / 4 / 256, 256, 0, stream>>>(x, xb, M_TOT * DIMN / 4);
  cast_w4_kernel<<<dim3(1024, 4), 256, 0, stream>>>(Wq, Wk, Wv, Wp, wqb, wkb, wvb, wpb);

  gemm_bt<0><<<1024, 256, 0, stream>>>(xb, wqb, qp, nullptr);
  gemm_bt<0><<<1024, 256, 0, stream>>>(xb, wkb, kp, nullptr);
  gemm_bt<1><<<1024, 256, 0, stream>>>(xb, wvb, vb, nullptr);

  hipMemsetAsync(kv, 0, 64 * 4096 * 4 + 64 * 64 * 4, stream);
  kv_state_kernel<<<512, 256, 0, stream>>>(kp, vb, kv, ks);
  prep_kv_kernel<<<64, 256, 0, stream>>>(kv, ks, kvb);

  attn_local_mfma<<<2048, 256, 0, stream>>>(qp, kvb, x, cw, cb, y);

  gemm_bt<2><<<1024, 256, 0, stream>>>(y, wpb, out, bp);
}

// Round 3
// 304.096 us; speedup vs baseline: 1.4144x; 1.1838x over previous
//
#include <hip/hip_runtime.h>
#include <hip/hip_bf16.h>
#include <stdint.h>

#define DIMN 1024
#define HEADS 16
#define HD 64
#define BATCH 4
#define SEQ 4096
#define M_TOT (BATCH*SEQ)   // 16384

typedef __attribute__((ext_vector_type(8))) __bf16 bf16x8;
typedef __attribute__((ext_vector_type(4))) __bf16 bf16x4;
typedef __attribute__((ext_vector_type(4))) float f32x4;

__device__ __forceinline__ void gload_lds16(const void* g, void* l) {
  __builtin_amdgcn_global_load_lds(
      (const __attribute__((address_space(1))) void*)(uintptr_t)g,
      (__attribute__((address_space(3))) void*)(uint32_t)(uintptr_t)l,
      16, 0, 0);
}

__device__ __forceinline__ uint32_t swz128(uint32_t off) {
  return off ^ (((off >> 7) & 7) << 4);
}

// ---------------- cast kernels ----------------
__global__ __launch_bounds__(256) void cast_x_kernel(const float* __restrict__ in,
                                                     __bf16* __restrict__ out, int n4) {
  int i = blockIdx.x * 256 + threadIdx.x;
  if (i < n4) {
    f32x4 v = ((const f32x4*)in)[i];
    bf16x4 o;
    o[0] = (__bf16)v[0]; o[1] = (__bf16)v[1]; o[2] = (__bf16)v[2]; o[3] = (__bf16)v[3];
    ((bf16x4*)out)[i] = o;
  }
}

__global__ __launch_bounds__(256) void cast_w4_kernel(const float* __restrict__ a,
                                                      const float* __restrict__ b,
                                                      const float* __restrict__ c,
                                                      const float* __restrict__ d,
                                                      __bf16* __restrict__ oa,
                                                      __bf16* __restrict__ ob,
                                                      __bf16* __restrict__ oc,
                                                      __bf16* __restrict__ od) {
  const float* srcs[4] = {a, b, c, d};
  __bf16* dsts[4] = {oa, ob, oc, od};
  const float* src = srcs[blockIdx.y];
  __bf16* dst = dsts[blockIdx.y];
  int i = blockIdx.x * 256 + threadIdx.x;
  f32x4 v = ((const f32x4*)src)[i];
  bf16x4 o;
  o[0] = (__bf16)v[0]; o[1] = (__bf16)v[1]; o[2] = (__bf16)v[2]; o[3] = (__bf16)v[3];
  ((bf16x4*)dst)[i] = o;
}

// ---------------- GEMM: C = A[M,K] @ W[N,K]^T ----------------
// MODE 2: v + bias -> f32 row-major [M,1024]
// MODE 3: fused QKV: col<1024 -> q (elu+1), <2048 -> k (elu+1), else v; bf16 head layout
#define BM 128
#define BN 128
#define BK 32

template <int MODE, int NT>
__global__ __launch_bounds__(256) void gemm_bt(const __bf16* __restrict__ A,
                                               const __bf16* __restrict__ Bw,
                                               void* __restrict__ Cout,
                                               const float* __restrict__ bias) {
  __shared__ __bf16 As[BM][BK];
  __shared__ __bf16 Bs[BN][BK];
  const int K = DIMN;
  const int bid = blockIdx.x;
  // XCD-aware swizzle: XCD x = bid&7 owns m-panels = x mod 8; n cycles innermost
  const int x = bid & 7, jj = bid >> 3;
  const int n_t = jj % NT;
  const int m_t = (jj / NT) * 8 + x;
  const int m0 = m_t * BM;
  const int n0 = n_t * BN;
  const int tid = threadIdx.x;
  const int lane = tid & 63;
  const int wave = tid >> 6;
  const int wr = wave >> 1, wc = wave & 1;

  f32x4 acc[4][4] = {};

  for (int k0 = 0; k0 < K; k0 += BK) {
#pragma unroll
    for (int t = 0; t < 2; ++t) {
      int chunk = t * 4 + wave;
      int e = (chunk * 1024 + lane * 16) >> 1;
      int row = e >> 5, col = e & 31;
      gload_lds16(A  + (size_t)(m0 + row) * K + k0 + col, ((char*)&As[0][0]) + chunk * 1024);
      gload_lds16(Bw + (size_t)(n0 + row) * K + k0 + col, ((char*)&Bs[0][0]) + chunk * 1024);
    }
    __syncthreads();

    bf16x8 af[4], bfr[4];
#pragma unroll
    for (int i = 0; i < 4; ++i) {
      af[i]  = *(const bf16x8*)&As[wr * 64 + i * 16 + (lane & 15)][(lane >> 4) * 8];
      bfr[i] = *(const bf16x8*)&Bs[wc * 64 + i * 16 + (lane & 15)][(lane >> 4) * 8];
    }
#pragma unroll
    for (int i = 0; i < 4; ++i)
#pragma unroll
      for (int j = 0; j < 4; ++j)
        acc[i][j] = __builtin_amdgcn_mfma_f32_16x16x32_bf16(af[i], bfr[j], acc[i][j], 0, 0, 0);
    __syncthreads();
  }

#pragma unroll
  for (int i = 0; i < 4; ++i) {
#pragma unroll
    for (int j = 0; j < 4; ++j) {
#pragma unroll
      for (int r = 0; r < 4; ++r) {
        int row = m0 + wr * 64 + i * 16 + (lane >> 4) * 4 + r;
        int col = n0 + wc * 64 + j * 16 + (lane & 15);
        float v = acc[i][j][r];
        if (MODE == 2) {
          ((float*)Cout)[(size_t)row * DIMN + col] = v + bias[col];
        } else {
          int wsel = col >> 10, c = col & 1023;
          if (wsel < 2) v = (v > 0.f) ? (v + 1.f) : __expf(v);
          int b = row >> 12, s = row & 4095;
          int h = c >> 6, e2 = c & 63;
          ((__bf16*)Cout)[(size_t)wsel * 16777216 +
                          ((size_t)((b * HEADS + h) * SEQ + s)) * HD + e2] = (__bf16)v;
        }
      }
    }
  }
}

// ---------------- kv_state via MFMA ----------------
// kv[bh][d][e] = sum_n K[n][d]*V[n][e]; ks via ones-column (VT row 64)
__global__ __launch_bounds__(256) void kv_state_mfma(const __bf16* __restrict__ kp,
                                                     const __bf16* __restrict__ vb,
                                                     float* __restrict__ kv,
                                                     float* __restrict__ ks) {
  __shared__ __bf16 kt[64][136];   // [d][n] transposed, padded
  __shared__ __bf16 vt[80][136];   // [e][n]; row 64 = ones, 65..79 = 0
  const int bid = blockIdx.x;      // 64 bh * 4 chunks
  const int bh = bid >> 2, nc = bid & 3;
  const int tid = threadIdx.x;
  const int lane = tid & 63;
  const int wave = tid >> 6;
  const int r16 = lane & 15, r4 = lane >> 4;

  for (int i = tid; i < 16 * 136; i += 256) {
    int rr = i / 136;
    vt[64 + rr][i - rr * 136] = (rr == 0) ? (__bf16)1.0f : (__bf16)0.0f;
  }

  const int trow = tid >> 1;            // n within tile (0..127)
  const int tcol = (tid & 1) * 32;      // d/e start

  f32x4 acc[5] = {};
  bf16x8 kr[4], vr[4];

  size_t gb = ((size_t)bh * SEQ + nc * 1024 + trow) * HD + tcol;
#pragma unroll
  for (int q = 0; q < 4; ++q) {
    kr[q] = *(const bf16x8*)(kp + gb + q * 8);
    vr[q] = *(const bf16x8*)(vb + gb + q * 8);
  }

  for (int t = 0; t < 8; ++t) {
    __syncthreads();
#pragma unroll
    for (int q = 0; q < 4; ++q)
#pragma unroll
      for (int j = 0; j < 8; ++j) {
        kt[tcol + q * 8 + j][trow] = kr[q][j];
        vt[tcol + q * 8 + j][trow] = vr[q][j];
      }
    __syncthreads();
    if (t < 7) {
      size_t gb2 = ((size_t)bh * SEQ + nc * 1024 + (t + 1) * 128 + trow) * HD + tcol;
#pragma unroll
      for (int q = 0; q < 4; ++q) {
        kr[q] = *(const bf16x8*)(kp + gb2 + q * 8);
        vr[q] = *(const bf16x8*)(vb + gb2 + q * 8);
      }
    }
#pragma unroll
    for (int ksl = 0; ksl < 4; ++ksl) {
      bf16x8 af = *(const bf16x8*)&kt[wave * 16 + r16][ksl * 32 + r4 * 8];
#pragma unroll
      for (int eb = 0; eb < 5; ++eb) {
        bf16x8 bf_ = *(const bf16x8*)&vt[eb * 16 + r16][ksl * 32 + r4 * 8];
        acc[eb] = __builtin_amdgcn_mfma_f32_16x16x32_bf16(af, bf_, acc[eb], 0, 0, 0);
      }
    }
  }

#pragma unroll
  for (int eb = 0; eb < 4; ++eb)
#pragma unroll
    for (int r = 0; r < 4; ++r) {
      int d = wave * 16 + r4 * 4 + r;
      atomicAdd(&kv[(size_t)bh * 4096 + d * 64 + eb * 16 + r16], acc[eb][r]);
    }
  if (r16 == 0) {
#pragma unroll
    for (int r = 0; r < 4; ++r)
      atomicAdd(&ks[bh * 64 + wave * 16 + r4 * 4 + r], acc[4][r]);
  }
}

// ---------------- prep: kvb[bh][80][64] bf16 = {kv^T ; k_state ; 0-pad} ----------------
__global__ __launch_bounds__(256) void prep_kv_kernel(const float* __restrict__ kv,
                                                      const float* __restrict__ ks,
                                                      __bf16* __restrict__ kvb) {
  const int bh = blockIdx.x;
  const int tid = threadIdx.x;
  for (int idx = tid; idx < 80 * 64; idx += 256) {
    int e = idx >> 6, d = idx & 63;
    float v;
    if (e < 64)       v = kv[(size_t)bh * 4096 + d * 64 + e];
    else if (e == 64) v = ks[bh * 64 + d];
    else              v = 0.f;
    kvb[(size_t)bh * 5120 + idx] = (__bf16)v;
  }
}

// ---------------- attn_out (MFMA) + depthwise conv -> y (bf16) ----------------
__global__ __launch_bounds__(256) void attn_local_mfma(const __bf16* __restrict__ qp,
                                                       const __bf16* __restrict__ kvb,
                                                       const float* __restrict__ x,
                                                       const float* __restrict__ conv_w,
                                                       const float* __restrict__ conv_b,
                                                       __bf16* __restrict__ y) {
  __shared__ __bf16 qs[128 * 64];
  __shared__ __bf16 bs[80 * 64];
  const int bid = blockIdx.x;       // 64 bh * 32 chunks
  const int bh = bid >> 5;
  const int chunk = bid & 31;
  const int tid = threadIdx.x;
  const int lane = tid & 63;
  const int wave = tid >> 6;
  const int r16 = lane & 15, r4 = lane >> 4;

  const char* qbase  = (const char*)(qp + ((size_t)bh * SEQ + chunk * 128) * HD);
  const char* kvbase = (const char*)(kvb + (size_t)bh * 5120);
#pragma unroll
  for (int t = 0; t < 4; ++t) {
    int c = t * 4 + wave;
    uint32_t off = c * 1024 + lane * 16;
    gload_lds16(qbase + swz128(off), ((char*)qs) + off);
  }
#pragma unroll
  for (int t = 0; t < 3; ++t) {
    int c = t * 4 + wave;
    if (c < 10) {
      uint32_t off = c * 1024 + lane * 16;
      gload_lds16(kvbase + swz128(off), ((char*)bs) + off);
    }
  }
  __syncthreads();

  f32x4 acc[2][5] = {};
#pragma unroll
  for (int kstep = 0; kstep < 2; ++kstep) {
    bf16x8 af[2], bfr[5];
#pragma unroll
    for (int i = 0; i < 2; ++i) {
      uint32_t off = (wave * 32 + i * 16 + r16) * 128 + kstep * 64 + r4 * 16;
      af[i] = *(const bf16x8*)(((char*)qs) + swz128(off));
    }
#pragma unroll
    for (int j = 0; j < 5; ++j) {
      uint32_t off = (j * 16 + r16) * 128 + kstep * 64 + r4 * 16;
      bfr[j] = *(const bf16x8*)(((char*)bs) + swz128(off));
    }
#pragma unroll
    for (int i = 0; i < 2; ++i)
#pragma unroll
      for (int j = 0; j < 5; ++j)
        acc[i][j] = __builtin_amdgcn_mfma_f32_16x16x32_bf16(af[i], bfr[j], acc[i][j], 0, 0, 0);
  }

  const int b = bh >> 4, h = bh & 15;
  float w0[4], w1[4], w2[4], bb[4];
#pragma unroll
  for (int j = 0; j < 4; ++j) {
    int c = h * HD + j * 16 + r16;
    w0[j] = conv_w[c * 3 + 0]; w1[j] = conv_w[c * 3 + 1]; w2[j] = conv_w[c * 3 + 2];
    bb[j] = conv_b[c];
  }
#pragma unroll
  for (int i = 0; i < 2; ++i) {
#pragma unroll
    for (int r = 0; r < 4; ++r) {
      int s = chunk * 128 + wave * 32 + i * 16 + r4 * 4 + r;
      size_t m = (size_t)b * SEQ + s;
      float den = fmaxf(__shfl(acc[i][4][r], lane & 48), 1e-6f);
      float inv = 1.0f / den;
#pragma unroll
      for (int j = 0; j < 4; ++j) {
        int c = h * HD + j * 16 + r16;
        float xm = x[m * DIMN + c];
        float xl = (s > 0)       ? x[(m - 1) * DIMN + c] : 0.f;
        float xr = (s < SEQ - 1) ? x[(m + 1) * DIMN + c] : 0.f;
        float val = acc[i][j][r] * inv
                  + xl * w0[j] + xm * w1[j] + xr * w2[j] + bb[j];
        y[m * DIMN + c] = (__bf16)val;
      }
    }
  }
}

// ---------------- launch ----------------
extern "C" void kernel_launch(void* const* d_in, const int* in_sizes, int n_in,
                              void* d_out, int out_size, void* d_ws, size_t ws_size,
                              hipStream_t stream) {
  const float* x  = (const float*)d_in[0];
  const float* Wq = (const float*)d_in[1];
  const float* Wk = (const float*)d_in[2];
  const float* Wv = (const float*)d_in[3];
  const float* Wp = (const float*)d_in[4];
  const float* bp = (const float*)d_in[5];
  const float* cw = (const float*)d_in[6];
  const float* cb = (const float*)d_in[7];
  float* out = (float*)d_out;

  char* ws = (char*)d_ws;
  const size_t MB = 1024 * 1024;
  __bf16* xb  = (__bf16*)(ws);             // 32 MB; later aliased as y
  __bf16* y   = xb;
  __bf16* qp  = (__bf16*)(ws + 32 * MB);   // q,k,v contiguous: qp + wsel*16777216
  __bf16* kp  = (__bf16*)(ws + 64 * MB);
  __bf16* vb  = (__bf16*)(ws + 96 * MB);
  __bf16* wqb = (__bf16*)(ws + 128 * MB);  // wq,wk,wv contiguous = fused [3072][1024]
  __bf16* wkb = (__bf16*)(ws + 130 * MB);
  __bf16* wvb = (__bf16*)(ws + 132 * MB);
  __bf16* wpb = (__bf16*)(ws + 134 * MB);
  float*  kv  = (float*)(ws + 136 * MB);
  float*  ks  = (float*)(ws + 137 * MB);
  __bf16* kvb = wqb;                       // wqb dead after QKV gemm

  cast_x_kernel<<<M_TOT * DIMN / 4 / 256, 256, 0, stream>>>(x, xb, M_TOT * DIMN / 4);
  cast_w4_kernel<<<dim3(1024, 4), 256, 0, stream>>>(Wq, Wk, Wv, Wp, wqb, wkb, wvb, wpb);

  // fused QKV: N = 3072, grid = 128 m-tiles * 24 n-tiles
  gemm_bt<3, 24><<<3072, 256, 0, stream>>>(xb, wqb, qp, nullptr);

  hipMemsetAsync(kv, 0, 64 * 4096 * 4 + 64 * 64 * 4, stream);
  kv_state_mfma<<<256, 256, 0, stream>>>(kp, vb, kv, ks);
  prep_kv_kernel<<<64, 256, 0, stream>>>(kv, ks, kvb);

  attn_local_mfma<<<2048, 256, 0, stream>>>(qp, kvb, x, cw, cb, y);

  gemm_bt<2, 8><<<1024, 256, 0, stream>>>(y, wpb, out, bp);
}

// Round 4
// 234.379 us; speedup vs baseline: 1.8351x; 1.2975x over previous
//
#include <hip/hip_runtime.h>
#include <hip/hip_bf16.h>
#include <stdint.h>

#define DIMN 1024
#define HEADS 16
#define HD 64
#define BATCH 4
#define SEQ 4096
#define M_TOT (BATCH*SEQ)   // 16384

typedef __attribute__((ext_vector_type(8))) __bf16 bf16x8;
typedef __attribute__((ext_vector_type(4))) __bf16 bf16x4;
typedef __attribute__((ext_vector_type(4))) float f32x4;

__device__ __forceinline__ void gload_lds16(const void* g, void* l) {
  __builtin_amdgcn_global_load_lds(
      (const __attribute__((address_space(1))) void*)(uintptr_t)g,
      (__attribute__((address_space(3))) void*)(uint32_t)(uintptr_t)l,
      16, 0, 0);
}

__device__ __forceinline__ uint32_t swz128(uint32_t off) {
  return off ^ (((off >> 7) & 7) << 4);
}

__device__ __forceinline__ void lfence() { asm volatile("" ::: "memory"); }
__device__ __forceinline__ void barx() { lfence(); __builtin_amdgcn_s_barrier(); lfence(); }

// ---------------- cast kernels ----------------
__global__ __launch_bounds__(256) void cast_x_kernel(const float* __restrict__ in,
                                                     __bf16* __restrict__ out, int n4) {
  int i = blockIdx.x * 256 + threadIdx.x;
  if (i < n4) {
    f32x4 v = ((const f32x4*)in)[i];
    bf16x4 o;
    o[0] = (__bf16)v[0]; o[1] = (__bf16)v[1]; o[2] = (__bf16)v[2]; o[3] = (__bf16)v[3];
    ((bf16x4*)out)[i] = o;
  }
}

__global__ __launch_bounds__(256) void cast_w4_kernel(const float* __restrict__ a,
                                                      const float* __restrict__ b,
                                                      const float* __restrict__ c,
                                                      const float* __restrict__ d,
                                                      __bf16* __restrict__ oa,
                                                      __bf16* __restrict__ ob,
                                                      __bf16* __restrict__ oc,
                                                      __bf16* __restrict__ od) {
  const float* srcs[4] = {a, b, c, d};
  __bf16* dsts[4] = {oa, ob, oc, od};
  const float* src = srcs[blockIdx.y];
  __bf16* dst = dsts[blockIdx.y];
  int i = blockIdx.x * 256 + threadIdx.x;
  f32x4 v = ((const f32x4*)src)[i];
  bf16x4 o;
  o[0] = (__bf16)v[0]; o[1] = (__bf16)v[1]; o[2] = (__bf16)v[2]; o[3] = (__bf16)v[3];
  ((bf16x4*)dst)[i] = o;
}

// ---------------- 256x256 8-phase GEMM: C = A[M,1024] @ W[N,1024]^T ----------------
// MODE 2: v + bias -> f32 row-major [M,1024]
// MODE 3: fused QKV: col<1024 -> q (elu+1), <2048 -> k (elu+1), else v; bf16 head layout
// 8 waves (2M x 4N), per-wave C = rows mf*32+wm*16 (mf 0..7), cols nf*64+wn*16 (nf 0..3)
// K-tiles of 64; double-buffered LDS; per-tile staging order B0,B1,A0,A1 at
// phase slots (ph2,ph3,ph4,next-ph1); boundary s_waitcnt vmcnt(6).
template <int MODE, int NT>
__global__ __launch_bounds__(512, 2) void gemm256(const __bf16* __restrict__ A,
                                                  const __bf16* __restrict__ Bw,
                                                  void* __restrict__ Cout,
                                                  const float* __restrict__ bias) {
  __shared__ char lds[131072];   // A: [0,65536) bufs 0/1; B: [65536,131072)
  const int KB = DIMN * 2;       // 2048 B row stride
  const int NKT = DIMN / 64;     // 16 K-tiles
  const int bid = blockIdx.x;
  const int x = bid & 7, jj = bid >> 3;
  const int n_t = jj % NT, m_t = (jj / NT) * 8 + x;
  const int m0 = m_t * 256, n0 = n_t * 256;
  const int tid = threadIdx.x;
  const int lane = tid & 63;
  const int wave = tid >> 6;
  const int wm = wave >> 2;        // 0..1
  const int wn = wave & 3;         // 0..3
  const int r16 = lane & 15, r4 = lane >> 4;

  // staging per-thread constants: off_i = i*8192 + tid*16
  const uint32_t s_off0 = tid * 16;
  const uint32_t s_off1 = 8192 + tid * 16;
  const uint32_t s_row0 = s_off0 >> 7, s_row1 = s_off1 >> 7;
  const uint32_t s_col0 = (s_off0 ^ ((s_row0 & 7) << 4)) & 127;
  const uint32_t s_col1 = (s_off1 ^ ((s_row1 & 7) << 4)) & 127;

  const char* Ab = (const char*)A + (size_t)m0 * KB;
  const char* Bb = (const char*)Bw + (size_t)n0 * KB;

  // stage half h of operand op (0=A,1=B) of k-tile kt into buffer b
  auto STAGE = [&](int op, int h, int kt, int b) {
    const char* gb = (op ? Bb : Ab) + (size_t)(h * 128) * KB + kt * 128;
    char* lb = lds + op * 65536 + b * 32768 + h * 16384;
    gload_lds16(gb + s_row0 * KB + s_col0, lb + s_off0);
    gload_lds16(gb + s_row1 * KB + s_col1, lb + s_off1);
  };

  // frag k-offsets (bytes within a row): k-half k at k*64 + r4*16, swizzled
  uint32_t axk[2];
#pragma unroll
  for (int k = 0; k < 2; ++k) axk[k] = (uint32_t)(k * 64 + r4 * 16) ^ ((r16 & 7) << 4);

  f32x4 acc[8][4] = {};
  bf16x8 bc[4][2];

  // prologue: B0,B1,A0,A1 (tile0) ; B0,B1,A0 (tile1)  [7 halves, 14 loads]
  STAGE(1, 0, 0, 0); STAGE(1, 1, 0, 0); STAGE(0, 0, 0, 0); STAGE(0, 1, 0, 0);
  STAGE(1, 0, 1, 1); STAGE(1, 1, 1, 1); STAGE(0, 0, 1, 1);
  asm volatile("s_waitcnt vmcnt(6)" ::: "memory");
  barx();

  for (int kt = 0; kt < NKT; ++kt) {
    const int p = kt & 1;
    const char* abuf = lds + p * 32768;
    const char* bbuf = lds + 65536 + p * 32768;

    // ---------- phase 1: all B + A mf{0,1}; stage A1(kt+1) ----------
    {
      bf16x8 af[2][2];
#pragma unroll
      for (int nf = 0; nf < 4; ++nf)
#pragma unroll
        for (int k = 0; k < 2; ++k)
          bc[nf][k] = *(const bf16x8*)(bbuf + (nf >> 1) * 16384 +
                        (((nf & 1) * 64 + wn * 16 + r16) << 7) + axk[k]);
#pragma unroll
      for (int i = 0; i < 2; ++i)
#pragma unroll
        for (int k = 0; k < 2; ++k)
          af[i][k] = *(const bf16x8*)(abuf + ((i * 32 + wm * 16 + r16) << 7) + axk[k]);
      if (kt + 1 < NKT) STAGE(0, 1, kt + 1, (kt + 1) & 1);
      barx();
      __builtin_amdgcn_s_setprio(1);
#pragma unroll
      for (int i = 0; i < 2; ++i)
#pragma unroll
        for (int nf = 0; nf < 4; ++nf)
#pragma unroll
          for (int k = 0; k < 2; ++k)
            acc[i][nf] = __builtin_amdgcn_mfma_f32_16x16x32_bf16(af[i][k], bc[nf][k], acc[i][nf], 0, 0, 0);
      __builtin_amdgcn_s_setprio(0);
      barx();
    }
    // ---------- phase 2: A mf{2,3}; stage B0(kt+2) ----------
    {
      bf16x8 af[2][2];
#pragma unroll
      for (int i = 0; i < 2; ++i)
#pragma unroll
        for (int k = 0; k < 2; ++k)
          af[i][k] = *(const bf16x8*)(abuf + (((2 + i) * 32 + wm * 16 + r16) << 7) + axk[k]);
      if (kt + 2 < NKT) STAGE(1, 0, kt + 2, p);
      barx();
      __builtin_amdgcn_s_setprio(1);
#pragma unroll
      for (int i = 0; i < 2; ++i)
#pragma unroll
        for (int nf = 0; nf < 4; ++nf)
#pragma unroll
          for (int k = 0; k < 2; ++k)
            acc[2 + i][nf] = __builtin_amdgcn_mfma_f32_16x16x32_bf16(af[i][k], bc[nf][k], acc[2 + i][nf], 0, 0, 0);
      __builtin_amdgcn_s_setprio(0);
      barx();
    }
    // ---------- phase 3: A mf{4,5} (half1); stage B1(kt+2) ----------
    {
      bf16x8 af[2][2];
#pragma unroll
      for (int i = 0; i < 2; ++i)
#pragma unroll
        for (int k = 0; k < 2; ++k)
          af[i][k] = *(const bf16x8*)(abuf + 16384 + ((i * 32 + wm * 16 + r16) << 7) + axk[k]);
      if (kt + 2 < NKT) STAGE(1, 1, kt + 2, p);
      barx();
      __builtin_amdgcn_s_setprio(1);
#pragma unroll
      for (int i = 0; i < 2; ++i)
#pragma unroll
        for (int nf = 0; nf < 4; ++nf)
#pragma unroll
          for (int k = 0; k < 2; ++k)
            acc[4 + i][nf] = __builtin_amdgcn_mfma_f32_16x16x32_bf16(af[i][k], bc[nf][k], acc[4 + i][nf], 0, 0, 0);
      __builtin_amdgcn_s_setprio(0);
      barx();
    }
    // ---------- phase 4: A mf{6,7} (half1); stage A0(kt+2); boundary vmcnt ----------
    {
      bf16x8 af[2][2];
#pragma unroll
      for (int i = 0; i < 2; ++i)
#pragma unroll
        for (int k = 0; k < 2; ++k)
          af[i][k] = *(const bf16x8*)(abuf + 16384 + (((2 + i) * 32 + wm * 16 + r16) << 7) + axk[k]);
      if (kt + 2 < NKT) STAGE(0, 0, kt + 2, p);
      if (kt == NKT - 2) { asm volatile("s_waitcnt vmcnt(0)" ::: "memory"); }
      else if (kt < NKT - 2) { asm volatile("s_waitcnt vmcnt(6)" ::: "memory"); }
      barx();
      __builtin_amdgcn_s_setprio(1);
#pragma unroll
      for (int i = 0; i < 2; ++i)
#pragma unroll
        for (int nf = 0; nf < 4; ++nf)
#pragma unroll
          for (int k = 0; k < 2; ++k)
            acc[6 + i][nf] = __builtin_amdgcn_mfma_f32_16x16x32_bf16(af[i][k], bc[nf][k], acc[6 + i][nf], 0, 0, 0);
      __builtin_amdgcn_s_setprio(0);
      barx();
    }
  }

  // ---------- epilogue ----------
#pragma unroll
  for (int mf = 0; mf < 8; ++mf) {
#pragma unroll
    for (int nf = 0; nf < 4; ++nf) {
#pragma unroll
      for (int r = 0; r < 4; ++r) {
        int row = m0 + mf * 32 + wm * 16 + r4 * 4 + r;
        int col = n0 + nf * 64 + wn * 16 + r16;
        float v = acc[mf][nf][r];
        if (MODE == 2) {
          ((float*)Cout)[(size_t)row * DIMN + col] = v + bias[col];
        } else {
          int wsel = col >> 10, c = col & 1023;
          if (wsel < 2) v = (v > 0.f) ? (v + 1.f) : __expf(v);
          int b = row >> 12, s = row & 4095;
          int h = c >> 6, e2 = c & 63;
          ((__bf16*)Cout)[(size_t)wsel * 16777216 +
                          ((size_t)((b * HEADS + h) * SEQ + s)) * HD + e2] = (__bf16)v;
        }
      }
    }
  }
}

// ---------------- kv_state via MFMA ----------------
__global__ __launch_bounds__(256) void kv_state_mfma(const __bf16* __restrict__ kp,
                                                     const __bf16* __restrict__ vb,
                                                     float* __restrict__ kv,
                                                     float* __restrict__ ks) {
  __shared__ __bf16 kt[64][136];
  __shared__ __bf16 vt[80][136];
  const int bid = blockIdx.x;      // 64 bh * 4 chunks
  const int bh = bid >> 2, nc = bid & 3;
  const int tid = threadIdx.x;
  const int lane = tid & 63;
  const int wave = tid >> 6;
  const int r16 = lane & 15, r4 = lane >> 4;

  for (int i = tid; i < 16 * 136; i += 256) {
    int rr = i / 136;
    vt[64 + rr][i - rr * 136] = (rr == 0) ? (__bf16)1.0f : (__bf16)0.0f;
  }

  const int trow = tid >> 1;
  const int tcol = (tid & 1) * 32;

  f32x4 acc[5] = {};
  bf16x8 kr[4], vr[4];

  size_t gb = ((size_t)bh * SEQ + nc * 1024 + trow) * HD + tcol;
#pragma unroll
  for (int q = 0; q < 4; ++q) {
    kr[q] = *(const bf16x8*)(kp + gb + q * 8);
    vr[q] = *(const bf16x8*)(vb + gb + q * 8);
  }

  for (int t = 0; t < 8; ++t) {
    __syncthreads();
#pragma unroll
    for (int q = 0; q < 4; ++q)
#pragma unroll
      for (int j = 0; j < 8; ++j) {
        kt[tcol + q * 8 + j][trow] = kr[q][j];
        vt[tcol + q * 8 + j][trow] = vr[q][j];
      }
    __syncthreads();
    if (t < 7) {
      size_t gb2 = ((size_t)bh * SEQ + nc * 1024 + (t + 1) * 128 + trow) * HD + tcol;
#pragma unroll
      for (int q = 0; q < 4; ++q) {
        kr[q] = *(const bf16x8*)(kp + gb2 + q * 8);
        vr[q] = *(const bf16x8*)(vb + gb2 + q * 8);
      }
    }
#pragma unroll
    for (int ksl = 0; ksl < 4; ++ksl) {
      bf16x8 af = *(const bf16x8*)&kt[wave * 16 + r16][ksl * 32 + r4 * 8];
#pragma unroll
      for (int eb = 0; eb < 5; ++eb) {
        bf16x8 bf_ = *(const bf16x8*)&vt[eb * 16 + r16][ksl * 32 + r4 * 8];
        acc[eb] = __builtin_amdgcn_mfma_f32_16x16x32_bf16(af, bf_, acc[eb], 0, 0, 0);
      }
    }
  }

#pragma unroll
  for (int eb = 0; eb < 4; ++eb)
#pragma unroll
    for (int r = 0; r < 4; ++r) {
      int d = wave * 16 + r4 * 4 + r;
      atomicAdd(&kv[(size_t)bh * 4096 + d * 64 + eb * 16 + r16], acc[eb][r]);
    }
  if (r16 == 0) {
#pragma unroll
    for (int r = 0; r < 4; ++r)
      atomicAdd(&ks[bh * 64 + wave * 16 + r4 * 4 + r], acc[4][r]);
  }
}

// ---------------- prep: kvb[bh][80][64] bf16 = {kv^T ; k_state ; 0-pad} ----------------
__global__ __launch_bounds__(256) void prep_kv_kernel(const float* __restrict__ kv,
                                                      const float* __restrict__ ks,
                                                      __bf16* __restrict__ kvb) {
  const int bh = blockIdx.x;
  const int tid = threadIdx.x;
  for (int idx = tid; idx < 80 * 64; idx += 256) {
    int e = idx >> 6, d = idx & 63;
    float v;
    if (e < 64)       v = kv[(size_t)bh * 4096 + d * 64 + e];
    else if (e == 64) v = ks[bh * 64 + d];
    else              v = 0.f;
    kvb[(size_t)bh * 5120 + idx] = (__bf16)v;
  }
}

// ---------------- attn_out (MFMA) + depthwise conv -> y (bf16) ----------------
__global__ __launch_bounds__(256) void attn_local_mfma(const __bf16* __restrict__ qp,
                                                       const __bf16* __restrict__ kvb,
                                                       const float* __restrict__ x,
                                                       const float* __restrict__ conv_w,
                                                       const float* __restrict__ conv_b,
                                                       __bf16* __restrict__ y) {
  __shared__ __bf16 qs[128 * 64];
  __shared__ __bf16 bs[80 * 64];
  const int bid = blockIdx.x;       // 64 bh * 32 chunks
  const int bh = bid >> 5;
  const int chunk = bid & 31;
  const int tid = threadIdx.x;
  const int lane = tid & 63;
  const int wave = tid >> 6;
  const int r16 = lane & 15, r4 = lane >> 4;

  const char* qbase  = (const char*)(qp + ((size_t)bh * SEQ + chunk * 128) * HD);
  const char* kvbase = (const char*)(kvb + (size_t)bh * 5120);
#pragma unroll
  for (int t = 0; t < 4; ++t) {
    int c = t * 4 + wave;
    uint32_t off = c * 1024 + lane * 16;
    gload_lds16(qbase + swz128(off), ((char*)qs) + off);
  }
#pragma unroll
  for (int t = 0; t < 3; ++t) {
    int c = t * 4 + wave;
    if (c < 10) {
      uint32_t off = c * 1024 + lane * 16;
      gload_lds16(kvbase + swz128(off), ((char*)bs) + off);
    }
  }
  __syncthreads();

  f32x4 acc[2][5] = {};
#pragma unroll
  for (int kstep = 0; kstep < 2; ++kstep) {
    bf16x8 af[2], bfr[5];
#pragma unroll
    for (int i = 0; i < 2; ++i) {
      uint32_t off = (wave * 32 + i * 16 + r16) * 128 + kstep * 64 + r4 * 16;
      af[i] = *(const bf16x8*)(((char*)qs) + swz128(off));
    }
#pragma unroll
    for (int j = 0; j < 5; ++j) {
      uint32_t off = (j * 16 + r16) * 128 + kstep * 64 + r4 * 16;
      bfr[j] = *(const bf16x8*)(((char*)bs) + swz128(off));
    }
#pragma unroll
    for (int i = 0; i < 2; ++i)
#pragma unroll
      for (int j = 0; j < 5; ++j)
        acc[i][j] = __builtin_amdgcn_mfma_f32_16x16x32_bf16(af[i], bfr[j], acc[i][j], 0, 0, 0);
  }

  const int b = bh >> 4, h = bh & 15;
  float w0[4], w1[4], w2[4], bb[4];
#pragma unroll
  for (int j = 0; j < 4; ++j) {
    int c = h * HD + j * 16 + r16;
    w0[j] = conv_w[c * 3 + 0]; w1[j] = conv_w[c * 3 + 1]; w2[j] = conv_w[c * 3 + 2];
    bb[j] = conv_b[c];
  }
#pragma unroll
  for (int i = 0; i < 2; ++i) {
#pragma unroll
    for (int r = 0; r < 4; ++r) {
      int s = chunk * 128 + wave * 32 + i * 16 + r4 * 4 + r;
      size_t m = (size_t)b * SEQ + s;
      float den = fmaxf(__shfl(acc[i][4][r], lane & 48), 1e-6f);
      float inv = 1.0f / den;
#pragma unroll
      for (int j = 0; j < 4; ++j) {
        int c = h * HD + j * 16 + r16;
        float xm = x[m * DIMN + c];
        float xl = (s > 0)       ? x[(m - 1) * DIMN + c] : 0.f;
        float xr = (s < SEQ - 1) ? x[(m + 1) * DIMN + c] : 0.f;
        float val = acc[i][j][r] * inv
                  + xl * w0[j] + xm * w1[j] + xr * w2[j] + bb[j];
        y[m * DIMN + c] = (__bf16)val;
      }
    }
  }
}

// ---------------- launch ----------------
extern "C" void kernel_launch(void* const* d_in, const int* in_sizes, int n_in,
                              void* d_out, int out_size, void* d_ws, size_t ws_size,
                              hipStream_t stream) {
  const float* x  = (const float*)d_in[0];
  const float* Wq = (const float*)d_in[1];
  const float* Wk = (const float*)d_in[2];
  const float* Wv = (const float*)d_in[3];
  const float* Wp = (const float*)d_in[4];
  const float* bp = (const float*)d_in[5];
  const float* cw = (const float*)d_in[6];
  const float* cb = (const float*)d_in[7];
  float* out = (float*)d_out;

  char* ws = (char*)d_ws;
  const size_t MB = 1024 * 1024;
  __bf16* xb  = (__bf16*)(ws);             // 32 MB; later aliased as y
  __bf16* y   = xb;
  __bf16* qp  = (__bf16*)(ws + 32 * MB);   // q,k,v contiguous: qp + wsel*16777216
  __bf16* kp  = (__bf16*)(ws + 64 * MB);
  __bf16* vb  = (__bf16*)(ws + 96 * MB);
  __bf16* wqb = (__bf16*)(ws + 128 * MB);  // wq,wk,wv contiguous = fused [3072][1024]
  __bf16* wkb = (__bf16*)(ws + 130 * MB);
  __bf16* wvb = (__bf16*)(ws + 132 * MB);
  __bf16* wpb = (__bf16*)(ws + 134 * MB);
  float*  kv  = (float*)(ws + 136 * MB);
  float*  ks  = (float*)(ws + 137 * MB);
  __bf16* kvb = wqb;                       // wqb dead after QKV gemm

  cast_x_kernel<<<M_TOT * DIMN / 4 / 256, 256, 0, stream>>>(x, xb, M_TOT * DIMN / 4);
  cast_w4_kernel<<<dim3(1024, 4), 256, 0, stream>>>(Wq, Wk, Wv, Wp, wqb, wkb, wvb, wpb);

  // fused QKV: M=16384, N=3072 -> 64 x 12 = 768 blocks
  gemm256<3, 12><<<768, 512, 0, stream>>>(xb, wqb, qp, nullptr);

  hipMemsetAsync(kv, 0, 64 * 4096 * 4 + 64 * 64 * 4, stream);
  kv_state_mfma<<<256, 256, 0, stream>>>(kp, vb, kv, ks);
  prep_kv_kernel<<<64, 256, 0, stream>>>(kv, ks, kvb);

  attn_local_mfma<<<2048, 256, 0, stream>>>(qp, kvb, x, cw, cb, y);

  // final: M=16384, N=1024 -> 64 x 4 = 256 blocks
  gemm256<2, 4><<<256, 512, 0, stream>>>(y, wpb, out, bp);
}